// Round 14
// baseline (50.721 us; speedup 1.0000x reference)
//
#include <hip/hip_runtime.h>
#include <hip/hip_bf16.h>
#include <stdint.h>

// Problem constants (B,S,D,K) = (2,4096,512,32)
#define S_LEN  4096
#define D_DIM  512
#define K_R    32
#define M_ROWS 8192

typedef __attribute__((ext_vector_type(8))) short bf16x8;
typedef __attribute__((ext_vector_type(4))) float f32x4;

__device__ __forceinline__ float bf2f(short u) {
  union { unsigned int i; float f; } c;
  c.i = ((unsigned int)(unsigned short)u) << 16;
  return c.f;
}

__device__ __forceinline__ void gload_lds16(const void* g, void* lds) {
  __builtin_amdgcn_global_load_lds(
      (__attribute__((address_space(1))) void*)g,
      (__attribute__((address_space(3))) void*)lds, 16, 0, 0);
}

__device__ __forceinline__ int4 pack8(float4 v0, float4 v1) {
  union { __hip_bfloat16 h[8]; int4 v; } u;
  u.h[0] = __float2bfloat16(v0.x); u.h[1] = __float2bfloat16(v0.y);
  u.h[2] = __float2bfloat16(v0.z); u.h[3] = __float2bfloat16(v0.w);
  u.h[4] = __float2bfloat16(v1.x); u.h[5] = __float2bfloat16(v1.y);
  u.h[6] = __float2bfloat16(v1.z); u.h[7] = __float2bfloat16(v1.w);
  return u.v;
}

// ---------------------------------------------------------------------------
// Kernel 1 (prep): R12-proven verbatim.
//   blocks [0,2048): cast x->bf16. [2048,2112): W_in->bf16. [2112,2176):
//   transpose-cast W_out -> WoutTb.
// ---------------------------------------------------------------------------
__global__ void __launch_bounds__(256) prep_kernel(
    const float* __restrict__ x, __hip_bfloat16* __restrict__ xb,
    const float* __restrict__ Win, __hip_bfloat16* __restrict__ Winb,
    const float* __restrict__ Wout, __hip_bfloat16* __restrict__ WoutTb) {
  __shared__ __hip_bfloat16 Lds[64][66];
  const int tid = threadIdx.x;
  if (blockIdx.x < 2048) {
    const int i = blockIdx.x * 256 + tid;
    const float4* xp = (const float4*)x;
    ((int4*)xb)[i] = pack8(xp[2 * i], xp[2 * i + 1]);
    return;
  }
  if (blockIdx.x < 2112) {
    const int e4 = ((blockIdx.x - 2048) * 256 + tid) * 4;
    const float4* wp = (const float4*)Win;
    int4* op = (int4*)Winb;
#pragma unroll
    for (int h = 0; h < 2; ++h)
      op[e4 / 2 + h] = pack8(wp[e4 + 2 * h], wp[e4 + 2 * h + 1]);
    return;
  }
  const int bx = blockIdx.x - 2112;
  const int tr = (bx >> 3) * 64;
  const int tc = (bx & 7) * 64;
#pragma unroll
  for (int it = 0; it < 4; ++it) {
    const int id = it * 256 + tid;
    const int r = id >> 4, c4 = (id & 15) * 4;
    const float4 v = *(const float4*)&Wout[(size_t)(tr + r) * 512 + tc + c4];
    Lds[r][c4]     = __float2bfloat16(v.x);
    Lds[r][c4 + 1] = __float2bfloat16(v.y);
    Lds[r][c4 + 2] = __float2bfloat16(v.z);
    Lds[r][c4 + 3] = __float2bfloat16(v.w);
  }
  __syncthreads();
#pragma unroll
  for (int it = 0; it < 2; ++it) {
    const int id = it * 256 + tid;
    const int j = id >> 3, i0 = (id & 7) * 8;
    union { __hip_bfloat16 h[8]; int4 v; } u;
#pragma unroll
    for (int r = 0; r < 8; ++r) u.h[r] = Lds[i0 + r][j];
    *(int4*)&WoutTb[(size_t)(tc + j) * 512 + tr + i0] = u.v;
  }
}

// ---------------------------------------------------------------------------
// Kernel 2 (mid): blocks [0,32): wcgemm (R12-proven verbatim).
//   blocks [32,544): gather, 16 rows/block, LDS route-window staging:
//     windows of 16 consecutive rows overlap (Cantor monotone) -> union of
//     routes usually < 48 rows; stage [lo,lo+48) once, gather from LDS.
//     Block-uniform fallback to direct-L2 reads when the span is wider.
// ---------------------------------------------------------------------------
#define BM 128
#define BN 64
#define BK 64
#define WCAP 48

union MidSMem {
  struct { __hip_bfloat16 As[BM][BK]; __hip_bfloat16 Bs[BN][BK]; } wc; // 24 KB
  struct { ushort X[WCAP * 512]; int r[16][32]; float w[16][32];
           int lo, hi; } ga;                                           // 53 KB
};

__global__ void __launch_bounds__(256) mid_kernel(
    const __hip_bfloat16* __restrict__ xb,
    const float* __restrict__ fw,
    const int* __restrict__ routes,
    __hip_bfloat16* __restrict__ g,
    const __hip_bfloat16* __restrict__ WoutTb,   // A  (m=j, k=p)
    const __hip_bfloat16* __restrict__ Winb,     // BT (n=q, k=p)
    __hip_bfloat16* __restrict__ WcT) {
  __shared__ MidSMem sm;
  const int tid = threadIdx.x;
  const int w = tid >> 6, l = tid & 63;

  if (blockIdx.x >= 32) {
    // ---- gather path: 16 rows, LDS window ----
    const int lin = blockIdx.x - 32;                 // [0,512)
    const int bchunk = (lin & 7) * 64 + (lin >> 3);  // XCD-contiguous groups
    const int r0 = bchunk * 16;
    const int s0 = r0 & (S_LEN - 1);
    const int b = r0 >> 12;                          // uniform (16 | 4096)
    if (tid == 0) { sm.ga.lo = 0x7fffffff; sm.ga.hi = 0; }
    __syncthreads();
#pragma unroll
    for (int it = 0; it < 2; ++it) {
      const int idx = it * 256 + tid;                // [0,512)
      const int rl = idx >> 5, k = idx & 31;
      const int rt = routes[(s0 + rl) * K_R + k];
      sm.ga.r[rl][k] = rt;
      sm.ga.w[rl][k] = fw[(s0 + rl) * K_R + k];
      atomicMin(&sm.ga.lo, rt);
      atomicMax(&sm.ga.hi, rt);
    }
    __syncthreads();
    const int lo = min(sm.ga.lo, S_LEN - WCAP);
    const bool staged = (sm.ga.hi - lo) < WCAP;      // block-uniform
    const __hip_bfloat16* xbat = xb + (size_t)b * S_LEN * D_DIM;
    if (staged) {
      // stage rows [lo, lo+48): 12 passes x 4 rows (256 thr x 16B)
#pragma unroll
      for (int it = 0; it < 12; ++it) {
        const int row = lo + it * 4 + (tid >> 6);
        gload_lds16(xbat + (size_t)row * D_DIM + l * 8,
                    sm.ga.X + it * 2048 + w * 512);
      }
    }
    __syncthreads();   // drains gload_lds before reads

#pragma unroll
    for (int rr = 0; rr < 4; ++rr) {
      const int rl = w * 4 + rr;
      const int row = r0 + rl;
      float acc[8] = {};
      if (staged) {
#pragma unroll 8
        for (int k = 0; k < K_R; ++k) {
          const float wk = sm.ga.w[rl][k];
          const int rt = sm.ga.r[rl][k] - lo;
          const bf16x8 v = *(const bf16x8*)(sm.ga.X + rt * 512 + l * 8);
#pragma unroll
          for (int j = 0; j < 8; ++j) acc[j] = fmaf(wk, bf2f(v[j]), acc[j]);
        }
      } else {
#pragma unroll 8
        for (int k = 0; k < K_R; ++k) {
          const float wk = sm.ga.w[rl][k];
          const bf16x8 v =
              *(const bf16x8*)(xbat + (size_t)sm.ga.r[rl][k] * D_DIM + l * 8);
#pragma unroll
          for (int j = 0; j < 8; ++j) acc[j] = fmaf(wk, bf2f(v[j]), acc[j]);
        }
      }
      union { __hip_bfloat16 h[8]; int4 v; } u;
#pragma unroll
      for (int j = 0; j < 8; ++j) u.h[j] = __float2bfloat16(acc[j]);
      *(int4*)(g + (size_t)row * D_DIM + l * 8) = u.v;
    }
    return;
  }

  // ---- wcgemm path: WcT[j][q] = sum_p WoutTb[j][p] * Winb[q][p] ----
  const int id2 = blockIdx.x;           // [0,32)
  const int bm0 = (id2 >> 3) * BM;
  const int bn0 = (id2 & 7) * BN;
  const int wr  = (w >> 1) * 64;
  const int wcn = (w & 1) * 32;

  const int rin = l >> 3;
  const int usw = (l & 7) ^ rin;
  const __hip_bfloat16* gA = WoutTb + (size_t)(bm0 + w * 8 + rin) * D_DIM + usw * 8;
  const __hip_bfloat16* gB = Winb   + (size_t)(bn0 + w * 8 + rin) * D_DIM + usw * 8;
  __hip_bfloat16* ldsA = &sm.wc.As[w * 8][0];
  __hip_bfloat16* ldsB = &sm.wc.Bs[w * 8][0];
  const int fr = l & 15, fq = l >> 4;

  f32x4 acc[4][2] = {};
  for (int k0 = 0; k0 < D_DIM; k0 += BK) {
#pragma unroll
    for (int i = 0; i < 4; ++i)
      gload_lds16(gA + (size_t)(i * 32) * D_DIM + k0, ldsA + i * 32 * BK);
#pragma unroll
    for (int j = 0; j < 2; ++j)
      gload_lds16(gB + (size_t)(j * 32) * D_DIM + k0, ldsB + j * 32 * BK);
    __syncthreads();
#pragma unroll
    for (int kk = 0; kk < 2; ++kk) {
      const int u = (kk * 4 + fq) ^ (fr & 7);
      bf16x8 af[4], bfv[2];
#pragma unroll
      for (int m = 0; m < 4; ++m)
        af[m] = *(const bf16x8*)&sm.wc.As[wr + m * 16 + fr][u * 8];
#pragma unroll
      for (int n = 0; n < 2; ++n)
        bfv[n] = *(const bf16x8*)&sm.wc.Bs[wcn + n * 16 + fr][u * 8];
#pragma unroll
      for (int m = 0; m < 4; ++m)
#pragma unroll
        for (int n = 0; n < 2; ++n)
          acc[m][n] = __builtin_amdgcn_mfma_f32_16x16x32_bf16(af[m], bfv[n], acc[m][n], 0, 0, 0);
    }
    __syncthreads();
  }
#pragma unroll
  for (int m = 0; m < 4; ++m)
#pragma unroll
    for (int n = 0; n < 2; ++n)
#pragma unroll
      for (int r = 0; r < 4; ++r) {
        const int grow = bm0 + wr + m * 16 + fq * 4 + r;
        const int gcol = bn0 + wcn + n * 16 + fr;
        WcT[(size_t)grow * D_DIM + gcol] = __float2bfloat16(acc[m][n][r]);
      }
}

// ---------------------------------------------------------------------------
// Kernel 3: out = x + g @ Wc + b_out   (R12-proven verbatim)
//   128x128 tile, 512 threads, 2-deep counted-vmcnt pipeline.
// ---------------------------------------------------------------------------
#define GBN 128

__global__ void __launch_bounds__(512, 4) gemm_out_kernel(
    const __hip_bfloat16* __restrict__ A,    // g (M x 512)
    const __hip_bfloat16* __restrict__ BT,   // WcT (n x k)
    const float* __restrict__ x,
    const float* __restrict__ b_out,
    float* __restrict__ out) {
  __shared__ __hip_bfloat16 As[2][BM][BK];    // 32 KB
  __shared__ __hip_bfloat16 Bs[2][GBN][BK];   // 32 KB
  const int tid = threadIdx.x;
  const int w = tid >> 6, l = tid & 63;

  const int bid = blockIdx.x;
  const int id2 = (bid & 7) * 32 + (bid >> 3);
  const int bm0 = (id2 >> 2) * BM;
  const int bn0 = (id2 & 3) * GBN;

  const int wr  = (w >> 2) * 64;
  const int wcn = (w & 3) * 32;

  const int rin = l >> 3;
  const int usw = (l & 7) ^ rin;
  const __hip_bfloat16* gA = A + (size_t)(bm0 + w * 16 + rin) * D_DIM + usw * 8;
  const __hip_bfloat16* gB = BT + (size_t)(bn0 + w * 16 + rin) * D_DIM + usw * 8;

  const int fr = l & 15, fq = l >> 4;
  f32x4 acc[4][2] = {};

#define STAGE(buf, k0)                                                          \
  {                                                                             \
    _Pragma("unroll")                                                           \
    for (int i = 0; i < 2; ++i)                                                 \
      gload_lds16(gA + (size_t)(i * 8) * D_DIM + (k0),                          \
                  &As[buf][w * 16 + i * 8][0]);                                 \
    _Pragma("unroll")                                                           \
    for (int j = 0; j < 2; ++j)                                                 \
      gload_lds16(gB + (size_t)(j * 8) * D_DIM + (k0),                          \
                  &Bs[buf][w * 16 + j * 8][0]);                                 \
  }

#define COMPUTE(buf)                                                            \
  {                                                                             \
    _Pragma("unroll")                                                           \
    for (int kk = 0; kk < 2; ++kk) {                                            \
      const int u = (kk * 4 + fq) ^ (fr & 7);                                   \
      bf16x8 af[4], bfv[2];                                                     \
      _Pragma("unroll")                                                         \
      for (int m = 0; m < 4; ++m)                                               \
        af[m] = *(const bf16x8*)&As[buf][wr + m * 16 + fr][u * 8];              \
      _Pragma("unroll")                                                         \
      for (int n = 0; n < 2; ++n)                                               \
        bfv[n] = *(const bf16x8*)&Bs[buf][wcn + n * 16 + fr][u * 8];            \
      _Pragma("unroll")                                                         \
      for (int m = 0; m < 4; ++m)                                               \
        _Pragma("unroll")                                                       \
        for (int n = 0; n < 2; ++n)                                             \
          acc[m][n] = __builtin_amdgcn_mfma_f32_16x16x32_bf16(                  \
              af[m], bfv[n], acc[m][n], 0, 0, 0);                               \
    }                                                                           \
  }

  STAGE(0, 0);
#pragma unroll
  for (int t = 0; t < 7; ++t) {
    STAGE((t + 1) & 1, (t + 1) * BK);
    asm volatile("s_waitcnt vmcnt(4)" ::: "memory");
    __builtin_amdgcn_s_barrier();
    __builtin_amdgcn_sched_barrier(0);
    COMPUTE(t & 1);
    __builtin_amdgcn_s_barrier();
  }
  asm volatile("s_waitcnt vmcnt(0)" ::: "memory");
  __builtin_amdgcn_s_barrier();
  __builtin_amdgcn_sched_barrier(0);
  COMPUTE(1);
#undef STAGE
#undef COMPUTE

  const float bb0 = b_out[bn0 + wcn + fr];
  const float bb1 = b_out[bn0 + wcn + 16 + fr];
#pragma unroll
  for (int m = 0; m < 4; ++m)
#pragma unroll
    for (int r = 0; r < 4; ++r) {
      const int grow = bm0 + wr + m * 16 + fq * 4 + r;
      const size_t base = (size_t)grow * D_DIM + bn0 + wcn + fr;
      out[base]      = acc[m][0][r] + x[base]      + bb0;
      out[base + 16] = acc[m][1][r] + x[base + 16] + bb1;
    }
}

// ---------------------------------------------------------------------------
extern "C" void kernel_launch(void* const* d_in, const int* in_sizes, int n_in,
                              void* d_out, int out_size, void* d_ws, size_t ws_size,
                              hipStream_t stream) {
  const float* x      = (const float*)d_in[0];
  const float* W_in   = (const float*)d_in[1];
  const float* W_out  = (const float*)d_in[2];
  const float* b_out  = (const float*)d_in[3];
  const float* fw     = (const float*)d_in[4];
  const int*   routes = (const int*)d_in[5];
  float* out = (float*)d_out;

  // workspace: Xb(8MB) | WcT(512KB) | g(8MB) | Winb(512KB) | WoutTb(512KB)
  char* ws = (char*)d_ws;
  __hip_bfloat16* Xb     = (__hip_bfloat16*)ws;
  __hip_bfloat16* WcT    = (__hip_bfloat16*)(ws + 8388608);
  __hip_bfloat16* g      = (__hip_bfloat16*)(ws + 8912896);
  __hip_bfloat16* Winb   = (__hip_bfloat16*)(ws + 17301504);
  __hip_bfloat16* WoutTb = (__hip_bfloat16*)(ws + 17825792);

  // 1) casts + transpose (R12-proven)
  prep_kernel<<<2176, 256, 0, stream>>>(x, Xb, W_in, Winb, W_out, WoutTb);
  // 2) wcgemm (32 blocks, first) || gather w/ LDS route-window (512 blocks)
  mid_kernel<<<544, 256, 0, stream>>>(Xb, fw, routes, g, WoutTb, Winb, WcT);
  // 3) out = x + g @ Wc + b_out  (128x128 tile, 2-deep counted-vmcnt)
  gemm_out_kernel<<<256, 512, 0, stream>>>(g, WcT, x, b_out, out);
}

// Round 15
// 35.049 us; speedup vs baseline: 1.4472x; 1.4472x over previous
//
#include <hip/hip_runtime.h>
#include <hip/hip_bf16.h>
#include <stdint.h>

// Problem constants (B,S,D,K) = (2,4096,512,32)
#define S_LEN  4096
#define D_DIM  512
#define K_R    32
#define M_ROWS 8192

typedef __attribute__((ext_vector_type(8))) short bf16x8;
typedef __attribute__((ext_vector_type(4))) float f32x4;

__device__ __forceinline__ float bf2f(short u) {
  union { unsigned int i; float f; } c;
  c.i = ((unsigned int)(unsigned short)u) << 16;
  return c.f;
}

__device__ __forceinline__ void gload_lds16(const void* g, void* lds) {
  __builtin_amdgcn_global_load_lds(
      (__attribute__((address_space(1))) void*)g,
      (__attribute__((address_space(3))) void*)lds, 16, 0, 0);
}

__device__ __forceinline__ int4 pack8(float4 v0, float4 v1) {
  union { __hip_bfloat16 h[8]; int4 v; } u;
  u.h[0] = __float2bfloat16(v0.x); u.h[1] = __float2bfloat16(v0.y);
  u.h[2] = __float2bfloat16(v0.z); u.h[3] = __float2bfloat16(v0.w);
  u.h[4] = __float2bfloat16(v1.x); u.h[5] = __float2bfloat16(v1.y);
  u.h[6] = __float2bfloat16(v1.z); u.h[7] = __float2bfloat16(v1.w);
  return u.v;
}

// ---------------------------------------------------------------------------
// Kernel 1 (prep): R12 + XCD-aligned x-cast.
//   blocks [0,2048): cast x->bf16 with the SAME chunk swizzle as the gather,
//     so each Xb row is written into the L2 of the XCD that will gather it.
//   [2048,2112): W_in->bf16. [2112,2176): transpose-cast W_out -> WoutTb.
// ---------------------------------------------------------------------------
__global__ void __launch_bounds__(256) prep_kernel(
    const float* __restrict__ x, __hip_bfloat16* __restrict__ xb,
    const float* __restrict__ Win, __hip_bfloat16* __restrict__ Winb,
    const float* __restrict__ Wout, __hip_bfloat16* __restrict__ WoutTb) {
  __shared__ __hip_bfloat16 Lds[64][66];
  const int tid = threadIdx.x;
  if (blockIdx.x < 2048) {
    const int lin = blockIdx.x;
    const int chunk = (lin & 7) * 256 + (lin >> 3);   // XCD-chunked (as mid)
    const int i = chunk * 256 + tid;
    const float4* xp = (const float4*)x;
    ((int4*)xb)[i] = pack8(xp[2 * i], xp[2 * i + 1]);
    return;
  }
  if (blockIdx.x < 2112) {
    const int e4 = ((blockIdx.x - 2048) * 256 + tid) * 4;
    const float4* wp = (const float4*)Win;
    int4* op = (int4*)Winb;
#pragma unroll
    for (int h = 0; h < 2; ++h)
      op[e4 / 2 + h] = pack8(wp[e4 + 2 * h], wp[e4 + 2 * h + 1]);
    return;
  }
  const int bx = blockIdx.x - 2112;
  const int tr = (bx >> 3) * 64;
  const int tc = (bx & 7) * 64;
#pragma unroll
  for (int it = 0; it < 4; ++it) {
    const int id = it * 256 + tid;
    const int r = id >> 4, c4 = (id & 15) * 4;
    const float4 v = *(const float4*)&Wout[(size_t)(tr + r) * 512 + tc + c4];
    Lds[r][c4]     = __float2bfloat16(v.x);
    Lds[r][c4 + 1] = __float2bfloat16(v.y);
    Lds[r][c4 + 2] = __float2bfloat16(v.z);
    Lds[r][c4 + 3] = __float2bfloat16(v.w);
  }
  __syncthreads();
#pragma unroll
  for (int it = 0; it < 2; ++it) {
    const int id = it * 256 + tid;
    const int j = id >> 3, i0 = (id & 7) * 8;
    union { __hip_bfloat16 h[8]; int4 v; } u;
#pragma unroll
    for (int r = 0; r < 8; ++r) u.h[r] = Lds[i0 + r][j];
    *(int4*)&WoutTb[(size_t)(tc + j) * 512 + tr + i0] = u.v;
  }
}

// ---------------------------------------------------------------------------
// Kernel 2 (mid): R12-proven verbatim.
//   blocks [0,32): wcgemm WcT = WoutTb x Winb (runs first, hides under gather)
//   blocks [32,2080): gather g[row,:] = sum_k w[s,k]*Xb[b,route,:]
// ---------------------------------------------------------------------------
#define BM 128
#define BN 64
#define BK 64

__global__ void __launch_bounds__(256) mid_kernel(
    const __hip_bfloat16* __restrict__ xb,
    const float* __restrict__ fw,
    const int* __restrict__ routes,
    __hip_bfloat16* __restrict__ g,
    const __hip_bfloat16* __restrict__ WoutTb,   // A  (m=j, k=p)
    const __hip_bfloat16* __restrict__ Winb,     // BT (n=q, k=p)
    __hip_bfloat16* __restrict__ WcT) {
  __shared__ __hip_bfloat16 As[BM][BK];   // 16 KB
  __shared__ __hip_bfloat16 Bs[BN][BK];   //  8 KB
  __shared__ float w_s[4][K_R];
  __shared__ int   r_s[4][K_R];
  const int tid = threadIdx.x;
  const int w = tid >> 6, l = tid & 63;

  if (blockIdx.x >= 32) {
    // ---- gather path ----
    const int lin = blockIdx.x - 32;
    const int bchunk = (lin & 7) * 256 + (lin >> 3); // XCD-contiguous rows
    const int row = bchunk * 4 + w;
    const int s = row & (S_LEN - 1);
    const int b = row >> 12;
    if (l < K_R) {
      r_s[w][l] = routes[s * K_R + l];
      w_s[w][l] = fw[s * K_R + l];
    }
    __syncthreads();
    const __hip_bfloat16* xbb = xb + (size_t)b * S_LEN * D_DIM + l * 8;
    float acc[8] = {};
#pragma unroll 8
    for (int k = 0; k < K_R; ++k) {
      const float wk = w_s[w][k];
      const bf16x8 v = *(const bf16x8*)(xbb + (size_t)r_s[w][k] * D_DIM);
#pragma unroll
      for (int j = 0; j < 8; ++j) acc[j] = fmaf(wk, bf2f(v[j]), acc[j]);
    }
    union { __hip_bfloat16 h[8]; int4 v; } u;
#pragma unroll
    for (int j = 0; j < 8; ++j) u.h[j] = __float2bfloat16(acc[j]);
    *(int4*)(g + (size_t)row * D_DIM + l * 8) = u.v;
    return;
  }

  // ---- wcgemm path: WcT[j][q] = sum_p WoutTb[j][p] * Winb[q][p] ----
  const int id2 = blockIdx.x;           // [0,32)
  const int bm0 = (id2 >> 3) * BM;
  const int bn0 = (id2 & 7) * BN;
  const int wr  = (w >> 1) * 64;
  const int wcn = (w & 1) * 32;

  const int rin = l >> 3;
  const int usw = (l & 7) ^ rin;
  const __hip_bfloat16* gA = WoutTb + (size_t)(bm0 + w * 8 + rin) * D_DIM + usw * 8;
  const __hip_bfloat16* gB = Winb   + (size_t)(bn0 + w * 8 + rin) * D_DIM + usw * 8;
  __hip_bfloat16* ldsA = &As[w * 8][0];
  __hip_bfloat16* ldsB = &Bs[w * 8][0];
  const int fr = l & 15, fq = l >> 4;

  f32x4 acc[4][2] = {};
  for (int k0 = 0; k0 < D_DIM; k0 += BK) {
#pragma unroll
    for (int i = 0; i < 4; ++i)
      gload_lds16(gA + (size_t)(i * 32) * D_DIM + k0, ldsA + i * 32 * BK);
#pragma unroll
    for (int j = 0; j < 2; ++j)
      gload_lds16(gB + (size_t)(j * 32) * D_DIM + k0, ldsB + j * 32 * BK);
    __syncthreads();
#pragma unroll
    for (int kk = 0; kk < 2; ++kk) {
      const int u = (kk * 4 + fq) ^ (fr & 7);
      bf16x8 af[4], bfv[2];
#pragma unroll
      for (int m = 0; m < 4; ++m)
        af[m] = *(const bf16x8*)&As[wr + m * 16 + fr][u * 8];
#pragma unroll
      for (int n = 0; n < 2; ++n)
        bfv[n] = *(const bf16x8*)&Bs[wcn + n * 16 + fr][u * 8];
#pragma unroll
      for (int m = 0; m < 4; ++m)
#pragma unroll
        for (int n = 0; n < 2; ++n)
          acc[m][n] = __builtin_amdgcn_mfma_f32_16x16x32_bf16(af[m], bfv[n], acc[m][n], 0, 0, 0);
    }
    __syncthreads();
  }
#pragma unroll
  for (int m = 0; m < 4; ++m)
#pragma unroll
    for (int n = 0; n < 2; ++n)
#pragma unroll
      for (int r = 0; r < 4; ++r) {
        const int grow = bm0 + wr + m * 16 + fq * 4 + r;
        const int gcol = bn0 + wcn + n * 16 + fr;
        WcT[(size_t)grow * D_DIM + gcol] = __float2bfloat16(acc[m][n][r]);
      }
}

// ---------------------------------------------------------------------------
// Kernel 3: out = x + g @ Wc + b_out   (R12-proven verbatim)
//   128x128 tile, 512 threads, 2-deep counted-vmcnt pipeline.
// ---------------------------------------------------------------------------
#define GBN 128

__global__ void __launch_bounds__(512, 4) gemm_out_kernel(
    const __hip_bfloat16* __restrict__ A,    // g (M x 512)
    const __hip_bfloat16* __restrict__ BT,   // WcT (n x k)
    const float* __restrict__ x,
    const float* __restrict__ b_out,
    float* __restrict__ out) {
  __shared__ __hip_bfloat16 As[2][BM][BK];    // 32 KB
  __shared__ __hip_bfloat16 Bs[2][GBN][BK];   // 32 KB
  const int tid = threadIdx.x;
  const int w = tid >> 6, l = tid & 63;

  const int bid = blockIdx.x;
  const int id2 = (bid & 7) * 32 + (bid >> 3);
  const int bm0 = (id2 >> 2) * BM;
  const int bn0 = (id2 & 3) * GBN;

  const int wr  = (w >> 2) * 64;
  const int wcn = (w & 3) * 32;

  const int rin = l >> 3;
  const int usw = (l & 7) ^ rin;
  const __hip_bfloat16* gA = A + (size_t)(bm0 + w * 16 + rin) * D_DIM + usw * 8;
  const __hip_bfloat16* gB = BT + (size_t)(bn0 + w * 16 + rin) * D_DIM + usw * 8;

  const int fr = l & 15, fq = l >> 4;
  f32x4 acc[4][2] = {};

#define STAGE(buf, k0)                                                          \
  {                                                                             \
    _Pragma("unroll")                                                           \
    for (int i = 0; i < 2; ++i)                                                 \
      gload_lds16(gA + (size_t)(i * 8) * D_DIM + (k0),                          \
                  &As[buf][w * 16 + i * 8][0]);                                 \
    _Pragma("unroll")                                                           \
    for (int j = 0; j < 2; ++j)                                                 \
      gload_lds16(gB + (size_t)(j * 8) * D_DIM + (k0),                          \
                  &Bs[buf][w * 16 + j * 8][0]);                                 \
  }

#define COMPUTE(buf)                                                            \
  {                                                                             \
    _Pragma("unroll")                                                           \
    for (int kk = 0; kk < 2; ++kk) {                                            \
      const int u = (kk * 4 + fq) ^ (fr & 7);                                   \
      bf16x8 af[4], bfv[2];                                                     \
      _Pragma("unroll")                                                         \
      for (int m = 0; m < 4; ++m)                                               \
        af[m] = *(const bf16x8*)&As[buf][wr + m * 16 + fr][u * 8];              \
      _Pragma("unroll")                                                         \
      for (int n = 0; n < 2; ++n)                                               \
        bfv[n] = *(const bf16x8*)&Bs[buf][wcn + n * 16 + fr][u * 8];            \
      _Pragma("unroll")                                                         \
      for (int m = 0; m < 4; ++m)                                               \
        _Pragma("unroll")                                                       \
        for (int n = 0; n < 2; ++n)                                             \
          acc[m][n] = __builtin_amdgcn_mfma_f32_16x16x32_bf16(                  \
              af[m], bfv[n], acc[m][n], 0, 0, 0);                               \
    }                                                                           \
  }

  STAGE(0, 0);
#pragma unroll
  for (int t = 0; t < 7; ++t) {
    STAGE((t + 1) & 1, (t + 1) * BK);
    asm volatile("s_waitcnt vmcnt(4)" ::: "memory");
    __builtin_amdgcn_s_barrier();
    __builtin_amdgcn_sched_barrier(0);
    COMPUTE(t & 1);
    __builtin_amdgcn_s_barrier();
  }
  asm volatile("s_waitcnt vmcnt(0)" ::: "memory");
  __builtin_amdgcn_s_barrier();
  __builtin_amdgcn_sched_barrier(0);
  COMPUTE(1);
#undef STAGE
#undef COMPUTE

  const float bb0 = b_out[bn0 + wcn + fr];
  const float bb1 = b_out[bn0 + wcn + 16 + fr];
#pragma unroll
  for (int m = 0; m < 4; ++m)
#pragma unroll
    for (int r = 0; r < 4; ++r) {
      const int grow = bm0 + wr + m * 16 + fq * 4 + r;
      const size_t base = (size_t)grow * D_DIM + bn0 + wcn + fr;
      out[base]      = acc[m][0][r] + x[base]      + bb0;
      out[base + 16] = acc[m][1][r] + x[base + 16] + bb1;
    }
}

// ---------------------------------------------------------------------------
extern "C" void kernel_launch(void* const* d_in, const int* in_sizes, int n_in,
                              void* d_out, int out_size, void* d_ws, size_t ws_size,
                              hipStream_t stream) {
  const float* x      = (const float*)d_in[0];
  const float* W_in   = (const float*)d_in[1];
  const float* W_out  = (const float*)d_in[2];
  const float* b_out  = (const float*)d_in[3];
  const float* fw     = (const float*)d_in[4];
  const int*   routes = (const int*)d_in[5];
  float* out = (float*)d_out;

  // workspace: Xb(8MB) | WcT(512KB) | g(8MB) | Winb(512KB) | WoutTb(512KB)
  char* ws = (char*)d_ws;
  __hip_bfloat16* Xb     = (__hip_bfloat16*)ws;
  __hip_bfloat16* WcT    = (__hip_bfloat16*)(ws + 8388608);
  __hip_bfloat16* g      = (__hip_bfloat16*)(ws + 8912896);
  __hip_bfloat16* Winb   = (__hip_bfloat16*)(ws + 17301504);
  __hip_bfloat16* WoutTb = (__hip_bfloat16*)(ws + 17825792);

  // 1) casts + transpose, x-cast XCD-aligned with the gather's row chunking
  prep_kernel<<<2176, 256, 0, stream>>>(x, Xb, W_in, Winb, W_out, WoutTb);
  // 2) wcgemm (32 blocks, first) || gather (2048 blocks)  (R12-proven)
  mid_kernel<<<2080, 256, 0, stream>>>(Xb, fw, routes, g, WoutTb, Winb, WcT);
  // 3) out = x + g @ Wc + b_out  (128x128 tile, 2-deep counted-vmcnt)
  gemm_out_kernel<<<256, 512, 0, stream>>>(g, WcT, x, b_out, out);
}